// Round 21
// baseline (172.213 us; speedup 1.0000x reference)
//
#include <hip/hip_runtime.h>

typedef __attribute__((ext_vector_type(8))) short bf16x8;
typedef __attribute__((ext_vector_type(4))) float f32x4;
typedef __attribute__((ext_vector_type(4))) unsigned short us4;
typedef __attribute__((ext_vector_type(4))) unsigned int u32x4;
typedef unsigned short us;

#define C2 0.18033688011112042f  /* SCALE * log2(e): Q pre-scale -> exp2-domain scores */

__device__ __forceinline__ unsigned short f2bf(float f) {
    unsigned int u = __float_as_uint(f);
    u = (u + 0x7FFF + ((u >> 16) & 1)) >> 16;   // RNE
    return (unsigned short)u;
}

// ---------------- prep kernels (merged dispatches; bodies proven) ----------

// blocks [0,4096): x fp32 -> bf16.  blocks [4096,12288): mask int32 -> bytes.
__global__ __launch_bounds__(256) void prep(const float* __restrict__ X,
                                            unsigned short* __restrict__ O,
                                            const int* __restrict__ Mi,
                                            unsigned int* __restrict__ Mo) {
    int bx = blockIdx.x;
    if (bx < 4096) {
        int i = bx * 256 + threadIdx.x;
        float4 v = ((const float4*)X)[i];
        us4 o;
        o.x = f2bf(v.x); o.y = f2bf(v.y); o.z = f2bf(v.z); o.w = f2bf(v.w);
        ((us4*)O)[i] = o;
    } else {
        int i = (bx - 4096) * 256 + threadIdx.x;
        int4 v = ((const int4*)Mi)[i];
        Mo[i] = (unsigned)(v.x & 1) | ((unsigned)(v.y & 1) << 8) |
                ((unsigned)(v.z & 1) << 16) | ((unsigned)(v.w & 1) << 24);
    }
}

// W [Kd][Cd] fp32 -> WT [Cd][Kd] bf16; two weight matrices in one launch.
__global__ __launch_bounds__(256) void transposew2(const float* __restrict__ W0,
                                                   unsigned short* __restrict__ WT0,
                                                   const float* __restrict__ W1,
                                                   unsigned short* __restrict__ WT1) {
    const float* W; unsigned short* WT; int Cd; int bx = blockIdx.x;
    if (bx < 96) { W = W0; WT = WT0; Cd = 3072; }
    else         { W = W1; WT = WT1; Cd = 1024; bx -= 96; }
    const int Kd = 1024;
    __shared__ float t[32][33];
    int c0 = bx * 32, k0 = blockIdx.y * 32;
    int tx = threadIdx.x & 31, ty = threadIdx.x >> 5;  // ty 0..7
#pragma unroll
    for (int i = 0; i < 32; i += 8)
        t[ty + i][tx] = W[(size_t)(k0 + ty + i) * Cd + c0 + tx];
    __syncthreads();
#pragma unroll
    for (int i = 0; i < 32; i += 8)
        WT[(size_t)(c0 + ty + i) * Kd + k0 + tx] = f2bf(t[tx][ty + i]);
}

// ---------------- GEMM: C = A[M][K] * BT[N][K]^T ----------------
// EXACT R14/R15 structure (proven pass pre+post).
template <int MODE>
__global__ __launch_bounds__(256) void gemm_bf16(
    const unsigned short* __restrict__ A, const unsigned short* __restrict__ BT,
    int M, int N, int K,
    unsigned short* __restrict__ Qo, unsigned short* __restrict__ Ko,
    unsigned short* __restrict__ Vo,
    const float* __restrict__ bias, float* __restrict__ Co) {
    __shared__ unsigned short Asub[128 * 64];
    __shared__ unsigned short Bsub[128 * 64];
    const int bm = blockIdx.y, bn = blockIdx.x;
    const int tid = threadIdx.x, w = tid >> 6, lane = tid & 63;
    const int wr = w >> 1, wc = w & 1, l16 = lane & 15, lg = lane >> 4;

    f32x4 acc[4][4];
#pragma unroll
    for (int i = 0; i < 4; i++)
#pragma unroll
        for (int j = 0; j < 4; j++) acc[i][j] = (f32x4){0.f, 0.f, 0.f, 0.f};

    const int wbase = (tid & ~63) * 16;  // wave-uniform LDS offset

    const int nkt = K / 64;
    for (int kt = 0; kt < nkt; kt++) {
        const int k0 = kt * 64;
#pragma unroll
        for (int i = 0; i < 4; i++) {
            int slot = i * 256 + tid;
            int r = slot >> 3, blk = slot & 7;
            const us* srcA = A + (size_t)(bm * 128 + r) * K + k0 + ((blk ^ (r & 7)) << 3);
            __builtin_amdgcn_global_load_lds(
                (const __attribute__((address_space(1))) unsigned*)srcA,
                (__attribute__((address_space(3))) unsigned*)((char*)Asub + i * 4096 + wbase),
                16, 0, 0);
            const us* srcB = BT + (size_t)(bn * 128 + r) * K + k0 + ((blk ^ (r & 7)) << 3);
            __builtin_amdgcn_global_load_lds(
                (const __attribute__((address_space(1))) unsigned*)srcB,
                (__attribute__((address_space(3))) unsigned*)((char*)Bsub + i * 4096 + wbase),
                16, 0, 0);
        }
        asm volatile("s_waitcnt vmcnt(0)" ::: "memory");
        __builtin_amdgcn_sched_barrier(0);
        __syncthreads();
#pragma unroll
        for (int ks = 0; ks < 2; ks++) {
            bf16x8 af[4], bfr[4];
            int kk = ks * 32 + lg * 8;
#pragma unroll
            for (int i = 0; i < 4; i++) {
                int r = wr * 64 + i * 16 + l16;
                af[i] = *(bf16x8*)((char*)Asub + ((r * 128 + kk * 2) ^ ((r & 7) << 4)));
                int c = wc * 64 + i * 16 + l16;
                bfr[i] = *(bf16x8*)((char*)Bsub + ((c * 128 + kk * 2) ^ ((c & 7) << 4)));
            }
#pragma unroll
            for (int i = 0; i < 4; i++)
#pragma unroll
                for (int j = 0; j < 4; j++)
                    acc[i][j] = __builtin_amdgcn_mfma_f32_16x16x32_bf16(
                        af[i], bfr[j], acc[i][j], 0, 0, 0);
        }
        __syncthreads();
    }

    if (MODE == 0) {
#pragma unroll
        for (int i = 0; i < 4; i++) {
            int grow = bm * 128 + wr * 64 + i * 16 + lg * 4;
            int bb = grow >> 11, ll = grow & 2047;
#pragma unroll
            for (int j = 0; j < 4; j++) {
                int gcol = bn * 128 + wc * 64 + j * 16 + l16;
                int s = gcol >> 10, hh = (gcol >> 6) & 15, dd = gcol & 63;
                int bhh = bb * 16 + hh;
                if (s == 2) {
                    us4 pk;
                    pk.x = f2bf(acc[i][j][0]); pk.y = f2bf(acc[i][j][1]);
                    pk.z = f2bf(acc[i][j][2]); pk.w = f2bf(acc[i][j][3]);
                    *(us4*)(Vo + (size_t)(bhh * 64 + dd) * 2048 + ll) = pk;
                } else if (s == 0) {
                    // Q: pre-scale by C2 so QK^T lands in exp2 domain
                    unsigned short* dst = Qo + (size_t)(bhh * 2048 + ll) * 64 + dd;
#pragma unroll
                    for (int r = 0; r < 4; r++)
                        dst[(size_t)r * 64] = f2bf(acc[i][j][r] * C2);
                } else {
                    unsigned short* dst = Ko + (size_t)(bhh * 2048 + ll) * 64 + dd;
#pragma unroll
                    for (int r = 0; r < 4; r++) dst[(size_t)r * 64] = f2bf(acc[i][j][r]);
                }
            }
        }
    } else {
#pragma unroll
        for (int i = 0; i < 4; i++) {
            int grow = bm * 128 + wr * 64 + i * 16 + lg * 4;
#pragma unroll
            for (int j = 0; j < 4; j++) {
                int gcol = bn * 128 + wc * 64 + j * 16 + l16;
                float bv = bias[gcol];
#pragma unroll
                for (int r = 0; r < 4; r++)
                    Co[(size_t)(grow + r) * N + gcol] = acc[i][j][r] + bv;
            }
        }
    }
}

// ---------------- flash attention (8-wave, no-max, deferred l_r reduce) -----
// EXACT R19 body (best verified: 80.8 us) with one safe cut: since no-max
// softmax makes l_r a pure positive sum, the cross-lane reduction (2x
// shfl_xor per iter) is DEFERRED to a single epilogue reduction — each lane
// keeps its private partial over its 16 keys/iter; lanes {l16,+16,+32,+48}
// are summed once at the end. Removes 64 shfl + serial dep from the loop.
// (R20's BK=128 regressed: drain scales with bytes/barrier, reverted.)
__global__ __launch_bounds__(512, 4) void flash_attn(
    const us* __restrict__ Q, const us* __restrict__ Kt,
    const us* __restrict__ VT, const unsigned char* __restrict__ M8,
    us* __restrict__ Z) {
    __shared__ char lds[2][16384];   // per buf: K 0..8191, VT 8192..16383
    const int bh = blockIdx.y;
    const int b = bh >> 4, h = bh & 15;
    const int tid = threadIdx.x, w = tid >> 6, lane = tid & 63;
    const int l16 = lane & 15, lg = lane >> 4;
    const int qb0 = blockIdx.x * 128;
    const int qrow = qb0 + w * 16 + l16;

    const size_t kbh = (size_t)bh * 2048;
    const size_t vbh = (size_t)bh * 64;

    const us* Qp = Q + (size_t)(kbh + qrow) * 64 + lg * 8;
    bf16x8 qf0 = *(const bf16x8*)(Qp);
    bf16x8 qf1 = *(const bf16x8*)(Qp + 32);

    float l_r = 0.f;   // per-lane partial (this lane's 16 keys per tile)
    f32x4 oacc[4];
#pragma unroll
    for (int jd = 0; jd < 4; jd++) oacc[jd] = (f32x4){0.f, 0.f, 0.f, 0.f};

    // exchange source lanes (loop-invariant)
    const int L0 = l16 + (((2 * lg) & 3) << 4);
    const int L1 = l16 + (((2 * lg + 1) & 3) << 4);
    const bool hi = (lg >> 1) != 0;

    // loop-invariant LDS read offsets (swizzled)
    int koff[8], voff[8];
#pragma unroll
    for (int j = 0; j < 4; j++)
#pragma unroll
        for (int hh = 0; hh < 2; hh++)
            koff[2 * j + hh] = (16 * j + l16) * 128 + ((64 * hh + 16 * lg) ^ ((l16 & 7) << 4));
#pragma unroll
    for (int ks = 0; ks < 2; ks++)
#pragma unroll
        for (int jd = 0; jd < 4; jd++)
            voff[ks * 4 + jd] =
                8192 + (jd * 16 + l16) * 128 + ((64 * ks + 16 * lg) ^ ((l16 & 7) << 4));

    // this lane's q-row mask bytes; per (kt,j): 4 consecutive keys 16j+4lg+r
    const unsigned char* mrow = M8 + (size_t)(b * 2048 + qrow) * 2048 + 4 * lg;

    const int wbase = (tid & ~63) * 16;  // wave-uniform LDS offset (w*1024)

    // 512 threads: K tile = 512 slots (1/thread), V tile = 512 slots (1/thread)
    auto STAGE = [&](int bufi, int kt) {
        char* base = &lds[bufi][0];
        const int lk = kt * 64;
        {
            int r = tid >> 3, blk = tid & 7;
            const us* src = Kt + (kbh + lk + r) * 64 + ((blk ^ (r & 7)) << 3);
            __builtin_amdgcn_global_load_lds(
                (const __attribute__((address_space(1))) unsigned*)src,
                (__attribute__((address_space(3))) unsigned*)(base + wbase),
                16, 0, 0);
        }
        {
            int r = tid >> 3, blk = tid & 7;
            const us* src = VT + (vbh + r) * 2048 + lk + ((blk ^ (r & 7)) << 3);
            __builtin_amdgcn_global_load_lds(
                (const __attribute__((address_space(1))) unsigned*)src,
                (__attribute__((address_space(3))) unsigned*)(base + 8192 + wbase),
                16, 0, 0);
        }
    };

    STAGE(0, 0);
    asm volatile("s_waitcnt vmcnt(0) lgkmcnt(0)" ::: "memory");
    __builtin_amdgcn_sched_barrier(0);
    __syncthreads();
    int cur = 0;

    for (int kt = 0; kt < 32; kt++) {
        const int lk0 = kt * 64;
        if (kt < 31) STAGE(cur ^ 1, kt + 1);   // issue next tile; drained at barrier below
        // ---- mask bytes for this iter: direct global (hidden under QK^T) ----
        uchar4 mu[4];
#pragma unroll
        for (int j = 0; j < 4; j++)
            mu[j] = *(const uchar4*)(mrow + lk0 + 16 * j);
        char* Lb = &lds[cur][0];
        // ---- K fragments + QK^T (scores already exp2-domain) ----
        bf16x8 kf[8];
#pragma unroll
        for (int q8 = 0; q8 < 8; q8++) kf[q8] = *(const bf16x8*)(Lb + koff[q8]);
        f32x4 sacc[4];
#pragma unroll
        for (int j = 0; j < 4; j++) sacc[j] = (f32x4){0.f, 0.f, 0.f, 0.f};
#pragma unroll
        for (int j = 0; j < 4; j++) {
            sacc[j] = __builtin_amdgcn_mfma_f32_16x16x32_bf16(kf[2 * j], qf0, sacc[j], 0, 0, 0);
            sacc[j] = __builtin_amdgcn_mfma_f32_16x16x32_bf16(kf[2 * j + 1], qf1, sacc[j], 0, 0, 0);
        }
        // ---- p = exp2(s) * mask (no max subtraction); pack via v_perm ----
        unsigned W[4][2];
        float rs = 0.f;
#pragma unroll
        for (int j = 0; j < 4; j++) {
            float p0 = __builtin_amdgcn_exp2f(sacc[j][0]) * (float)mu[j].x;
            float p1 = __builtin_amdgcn_exp2f(sacc[j][1]) * (float)mu[j].y;
            float p2 = __builtin_amdgcn_exp2f(sacc[j][2]) * (float)mu[j].z;
            float p3 = __builtin_amdgcn_exp2f(sacc[j][3]) * (float)mu[j].w;
            rs += (p0 + p1) + (p2 + p3);
            W[j][0] = __builtin_amdgcn_perm(__float_as_uint(p1), __float_as_uint(p0),
                                            0x07060302u);
            W[j][1] = __builtin_amdgcn_perm(__float_as_uint(p3), __float_as_uint(p2),
                                            0x07060302u);
        }
        l_r += rs;   // per-lane partial; cross-lane reduce deferred to epilogue
        // ---- register-only P exchange + PV (V frags per ks-half) ----
#pragma unroll
        for (int ks = 0; ks < 2; ks++) {
            bf16x8 vf[4];
#pragma unroll
            for (int jd = 0; jd < 4; jd++)
                vf[jd] = *(const bf16x8*)(Lb + voff[ks * 4 + jd]);
            unsigned a0 = __shfl((int)W[2 * ks][0], L0), b0 = __shfl((int)W[2 * ks + 1][0], L0);
            unsigned a1 = __shfl((int)W[2 * ks][1], L0), b1 = __shfl((int)W[2 * ks + 1][1], L0);
            unsigned a2 = __shfl((int)W[2 * ks][0], L1), b2 = __shfl((int)W[2 * ks + 1][0], L1);
            unsigned a3 = __shfl((int)W[2 * ks][1], L1), b3 = __shfl((int)W[2 * ks + 1][1], L1);
            u32x4 pw = (u32x4){hi ? b0 : a0, hi ? b1 : a1, hi ? b2 : a2, hi ? b3 : a3};
            bf16x8 pB = __builtin_bit_cast(bf16x8, pw);
#pragma unroll
            for (int jd = 0; jd < 4; jd++)
                oacc[jd] = __builtin_amdgcn_mfma_f32_16x16x32_bf16(vf[jd], pB,
                                                                   oacc[jd], 0, 0, 0);
        }
        // explicit drain: stage(kt+1) landed + all LDS reads complete, THEN barrier
        asm volatile("s_waitcnt vmcnt(0) lgkmcnt(0)" ::: "memory");
        __builtin_amdgcn_sched_barrier(0);
        __syncthreads();
        cur ^= 1;
    }

    // epilogue: single cross-lane reduce over lg groups (keys partition)
    l_r += __shfl_xor(l_r, 16);
    l_r += __shfl_xor(l_r, 32);
    const float inv = 1.0f / (l_r + 1e-20f);
    us* zp = Z + (size_t)(b * 2048 + qrow) * 1024 + h * 64 + lg * 4;
#pragma unroll
    for (int jd = 0; jd < 4; jd++) {
        us4 pk;
        pk.x = f2bf(oacc[jd][0] * inv);
        pk.y = f2bf(oacc[jd][1] * inv);
        pk.z = f2bf(oacc[jd][2] * inv);
        pk.w = f2bf(oacc[jd][3] * inv);
        *(us4*)(zp + jd * 16) = pk;
    }
}

// ---------------- launcher ----------------

extern "C" void kernel_launch(void* const* d_in, const int* in_sizes, int n_in,
                              void* d_out, int out_size, void* d_ws, size_t ws_size,
                              hipStream_t stream) {
    const float* x = (const float*)d_in[0];
    const int* mask = (const int*)d_in[1];
    const float* Wqkv = (const float*)d_in[2];
    const float* Wout = (const float*)d_in[3];
    const float* bout = (const float*)d_in[4];
    float* out = (float*)d_out;
    char* ws = (char*)d_ws;

    // 48 MB layout (proven)
    unsigned short* xz    = (unsigned short*)(ws);               // 8 MB (x bf16, later Z bf16)
    unsigned short* wqkvT = (unsigned short*)(ws + (8u << 20));  // 6 MB
    unsigned short* woutT = (unsigned short*)(ws + (14u << 20)); // 2 MB
    unsigned char*  m8    = (unsigned char*)(ws + (16u << 20));  // 8 MB
    unsigned short* Qb    = (unsigned short*)(ws + (24u << 20)); // 8 MB
    unsigned short* Kb    = (unsigned short*)(ws + (32u << 20)); // 8 MB
    unsigned short* VTb   = (unsigned short*)(ws + (40u << 20)); // 8 MB

    prep<<<12288, 256, 0, stream>>>(x, xz, mask, (unsigned int*)m8);
    transposew2<<<dim3(128, 32), 256, 0, stream>>>(Wqkv, wqkvT, Wout, woutT);
    gemm_bf16<0><<<dim3(3072 / 128, 4096 / 128), 256, 0, stream>>>(
        xz, wqkvT, 4096, 3072, 1024, Qb, Kb, VTb, nullptr, nullptr);
    flash_attn<<<dim3(16, 32), 512, 0, stream>>>(Qb, Kb, VTb, m8, xz);
    gemm_bf16<1><<<dim3(1024 / 128, 4096 / 128), 256, 0, stream>>>(
        xz, woutT, 4096, 1024, 1024, nullptr, nullptr, nullptr, bout, out);
}

// Round 22
// 159.756 us; speedup vs baseline: 1.0780x; 1.0780x over previous
//
#include <hip/hip_runtime.h>

typedef __attribute__((ext_vector_type(8))) short bf16x8;
typedef __attribute__((ext_vector_type(4))) float f32x4;
typedef __attribute__((ext_vector_type(4))) unsigned short us4;
typedef __attribute__((ext_vector_type(4))) unsigned int u32x4;
typedef unsigned short us;

#define C2 0.18033688011112042f  /* SCALE * log2(e): Q pre-scale -> exp2-domain scores */

__device__ __forceinline__ unsigned short f2bf(float f) {
    unsigned int u = __float_as_uint(f);
    u = (u + 0x7FFF + ((u >> 16) & 1)) >> 16;   // RNE
    return (unsigned short)u;
}

// ---------------- prep kernels (merged dispatches; bodies proven) ----------

// blocks [0,4096): x fp32 -> bf16.  blocks [4096,12288): mask int32 -> bytes.
__global__ __launch_bounds__(256) void prep(const float* __restrict__ X,
                                            unsigned short* __restrict__ O,
                                            const int* __restrict__ Mi,
                                            unsigned int* __restrict__ Mo) {
    int bx = blockIdx.x;
    if (bx < 4096) {
        int i = bx * 256 + threadIdx.x;
        float4 v = ((const float4*)X)[i];
        us4 o;
        o.x = f2bf(v.x); o.y = f2bf(v.y); o.z = f2bf(v.z); o.w = f2bf(v.w);
        ((us4*)O)[i] = o;
    } else {
        int i = (bx - 4096) * 256 + threadIdx.x;
        int4 v = ((const int4*)Mi)[i];
        Mo[i] = (unsigned)(v.x & 1) | ((unsigned)(v.y & 1) << 8) |
                ((unsigned)(v.z & 1) << 16) | ((unsigned)(v.w & 1) << 24);
    }
}

// W [Kd][Cd] fp32 -> WT [Cd][Kd] bf16; two weight matrices in one launch.
__global__ __launch_bounds__(256) void transposew2(const float* __restrict__ W0,
                                                   unsigned short* __restrict__ WT0,
                                                   const float* __restrict__ W1,
                                                   unsigned short* __restrict__ WT1) {
    const float* W; unsigned short* WT; int Cd; int bx = blockIdx.x;
    if (bx < 96) { W = W0; WT = WT0; Cd = 3072; }
    else         { W = W1; WT = WT1; Cd = 1024; bx -= 96; }
    const int Kd = 1024;
    __shared__ float t[32][33];
    int c0 = bx * 32, k0 = blockIdx.y * 32;
    int tx = threadIdx.x & 31, ty = threadIdx.x >> 5;  // ty 0..7
#pragma unroll
    for (int i = 0; i < 32; i += 8)
        t[ty + i][tx] = W[(size_t)(k0 + ty + i) * Cd + c0 + tx];
    __syncthreads();
#pragma unroll
    for (int i = 0; i < 32; i += 8)
        WT[(size_t)(c0 + ty + i) * Kd + k0 + tx] = f2bf(t[tx][ty + i]);
}

// ---------------- GEMM: C = A[M][K] * BT[N][K]^T ----------------
// EXACT R14/R15 structure (proven pass pre+post).
template <int MODE>
__global__ __launch_bounds__(256) void gemm_bf16(
    const unsigned short* __restrict__ A, const unsigned short* __restrict__ BT,
    int M, int N, int K,
    unsigned short* __restrict__ Qo, unsigned short* __restrict__ Ko,
    unsigned short* __restrict__ Vo,
    const float* __restrict__ bias, float* __restrict__ Co) {
    __shared__ unsigned short Asub[128 * 64];
    __shared__ unsigned short Bsub[128 * 64];
    const int bm = blockIdx.y, bn = blockIdx.x;
    const int tid = threadIdx.x, w = tid >> 6, lane = tid & 63;
    const int wr = w >> 1, wc = w & 1, l16 = lane & 15, lg = lane >> 4;

    f32x4 acc[4][4];
#pragma unroll
    for (int i = 0; i < 4; i++)
#pragma unroll
        for (int j = 0; j < 4; j++) acc[i][j] = (f32x4){0.f, 0.f, 0.f, 0.f};

    const int wbase = (tid & ~63) * 16;  // wave-uniform LDS offset

    const int nkt = K / 64;
    for (int kt = 0; kt < nkt; kt++) {
        const int k0 = kt * 64;
#pragma unroll
        for (int i = 0; i < 4; i++) {
            int slot = i * 256 + tid;
            int r = slot >> 3, blk = slot & 7;
            const us* srcA = A + (size_t)(bm * 128 + r) * K + k0 + ((blk ^ (r & 7)) << 3);
            __builtin_amdgcn_global_load_lds(
                (const __attribute__((address_space(1))) unsigned*)srcA,
                (__attribute__((address_space(3))) unsigned*)((char*)Asub + i * 4096 + wbase),
                16, 0, 0);
            const us* srcB = BT + (size_t)(bn * 128 + r) * K + k0 + ((blk ^ (r & 7)) << 3);
            __builtin_amdgcn_global_load_lds(
                (const __attribute__((address_space(1))) unsigned*)srcB,
                (__attribute__((address_space(3))) unsigned*)((char*)Bsub + i * 4096 + wbase),
                16, 0, 0);
        }
        asm volatile("s_waitcnt vmcnt(0)" ::: "memory");
        __builtin_amdgcn_sched_barrier(0);
        __syncthreads();
#pragma unroll
        for (int ks = 0; ks < 2; ks++) {
            bf16x8 af[4], bfr[4];
            int kk = ks * 32 + lg * 8;
#pragma unroll
            for (int i = 0; i < 4; i++) {
                int r = wr * 64 + i * 16 + l16;
                af[i] = *(bf16x8*)((char*)Asub + ((r * 128 + kk * 2) ^ ((r & 7) << 4)));
                int c = wc * 64 + i * 16 + l16;
                bfr[i] = *(bf16x8*)((char*)Bsub + ((c * 128 + kk * 2) ^ ((c & 7) << 4)));
            }
#pragma unroll
            for (int i = 0; i < 4; i++)
#pragma unroll
                for (int j = 0; j < 4; j++)
                    acc[i][j] = __builtin_amdgcn_mfma_f32_16x16x32_bf16(
                        af[i], bfr[j], acc[i][j], 0, 0, 0);
        }
        __syncthreads();
    }

    if (MODE == 0) {
#pragma unroll
        for (int i = 0; i < 4; i++) {
            int grow = bm * 128 + wr * 64 + i * 16 + lg * 4;
            int bb = grow >> 11, ll = grow & 2047;
#pragma unroll
            for (int j = 0; j < 4; j++) {
                int gcol = bn * 128 + wc * 64 + j * 16 + l16;
                int s = gcol >> 10, hh = (gcol >> 6) & 15, dd = gcol & 63;
                int bhh = bb * 16 + hh;
                if (s == 2) {
                    us4 pk;
                    pk.x = f2bf(acc[i][j][0]); pk.y = f2bf(acc[i][j][1]);
                    pk.z = f2bf(acc[i][j][2]); pk.w = f2bf(acc[i][j][3]);
                    *(us4*)(Vo + (size_t)(bhh * 64 + dd) * 2048 + ll) = pk;
                } else if (s == 0) {
                    // Q: pre-scale by C2 so QK^T lands in exp2 domain
                    unsigned short* dst = Qo + (size_t)(bhh * 2048 + ll) * 64 + dd;
#pragma unroll
                    for (int r = 0; r < 4; r++)
                        dst[(size_t)r * 64] = f2bf(acc[i][j][r] * C2);
                } else {
                    unsigned short* dst = Ko + (size_t)(bhh * 2048 + ll) * 64 + dd;
#pragma unroll
                    for (int r = 0; r < 4; r++) dst[(size_t)r * 64] = f2bf(acc[i][j][r]);
                }
            }
        }
    } else {
#pragma unroll
        for (int i = 0; i < 4; i++) {
            int grow = bm * 128 + wr * 64 + i * 16 + lg * 4;
#pragma unroll
            for (int j = 0; j < 4; j++) {
                int gcol = bn * 128 + wc * 64 + j * 16 + l16;
                float bv = bias[gcol];
#pragma unroll
                for (int r = 0; r < 4; r++)
                    Co[(size_t)(grow + r) * N + gcol] = acc[i][j][r] + bv;
            }
        }
    }
}

// ---------------- flash attention (8-wave, no-max softmax) ------------------
// EXACT R19 body (best verified: 80.8 us flash, 159.6 total). R21's deferred
// l_r reduce regressed (-11 us): the per-iter shfl pair was filling the
// drain-shadow; keep it.
__global__ __launch_bounds__(512, 4) void flash_attn(
    const us* __restrict__ Q, const us* __restrict__ Kt,
    const us* __restrict__ VT, const unsigned char* __restrict__ M8,
    us* __restrict__ Z) {
    __shared__ char lds[2][16384];   // per buf: K 0..8191, VT 8192..16383
    const int bh = blockIdx.y;
    const int b = bh >> 4, h = bh & 15;
    const int tid = threadIdx.x, w = tid >> 6, lane = tid & 63;
    const int l16 = lane & 15, lg = lane >> 4;
    const int qb0 = blockIdx.x * 128;
    const int qrow = qb0 + w * 16 + l16;

    const size_t kbh = (size_t)bh * 2048;
    const size_t vbh = (size_t)bh * 64;

    const us* Qp = Q + (size_t)(kbh + qrow) * 64 + lg * 8;
    bf16x8 qf0 = *(const bf16x8*)(Qp);
    bf16x8 qf1 = *(const bf16x8*)(Qp + 32);

    float l_r = 0.f;
    f32x4 oacc[4];
#pragma unroll
    for (int jd = 0; jd < 4; jd++) oacc[jd] = (f32x4){0.f, 0.f, 0.f, 0.f};

    // exchange source lanes (loop-invariant)
    const int L0 = l16 + (((2 * lg) & 3) << 4);
    const int L1 = l16 + (((2 * lg + 1) & 3) << 4);
    const bool hi = (lg >> 1) != 0;

    // loop-invariant LDS read offsets (swizzled)
    int koff[8], voff[8];
#pragma unroll
    for (int j = 0; j < 4; j++)
#pragma unroll
        for (int hh = 0; hh < 2; hh++)
            koff[2 * j + hh] = (16 * j + l16) * 128 + ((64 * hh + 16 * lg) ^ ((l16 & 7) << 4));
#pragma unroll
    for (int ks = 0; ks < 2; ks++)
#pragma unroll
        for (int jd = 0; jd < 4; jd++)
            voff[ks * 4 + jd] =
                8192 + (jd * 16 + l16) * 128 + ((64 * ks + 16 * lg) ^ ((l16 & 7) << 4));

    // this lane's q-row mask bytes; per (kt,j): 4 consecutive keys 16j+4lg+r
    const unsigned char* mrow = M8 + (size_t)(b * 2048 + qrow) * 2048 + 4 * lg;

    const int wbase = (tid & ~63) * 16;  // wave-uniform LDS offset (w*1024)

    // 512 threads: K tile = 512 slots (1/thread), V tile = 512 slots (1/thread)
    auto STAGE = [&](int bufi, int kt) {
        char* base = &lds[bufi][0];
        const int lk = kt * 64;
        {
            int r = tid >> 3, blk = tid & 7;
            const us* src = Kt + (kbh + lk + r) * 64 + ((blk ^ (r & 7)) << 3);
            __builtin_amdgcn_global_load_lds(
                (const __attribute__((address_space(1))) unsigned*)src,
                (__attribute__((address_space(3))) unsigned*)(base + wbase),
                16, 0, 0);
        }
        {
            int r = tid >> 3, blk = tid & 7;
            const us* src = VT + (vbh + r) * 2048 + lk + ((blk ^ (r & 7)) << 3);
            __builtin_amdgcn_global_load_lds(
                (const __attribute__((address_space(1))) unsigned*)src,
                (__attribute__((address_space(3))) unsigned*)(base + 8192 + wbase),
                16, 0, 0);
        }
    };

    STAGE(0, 0);
    asm volatile("s_waitcnt vmcnt(0) lgkmcnt(0)" ::: "memory");
    __builtin_amdgcn_sched_barrier(0);
    __syncthreads();
    int cur = 0;

    for (int kt = 0; kt < 32; kt++) {
        const int lk0 = kt * 64;
        if (kt < 31) STAGE(cur ^ 1, kt + 1);   // issue next tile; drained at barrier below
        // ---- mask bytes for this iter: direct global (hidden under QK^T) ----
        uchar4 mu[4];
#pragma unroll
        for (int j = 0; j < 4; j++)
            mu[j] = *(const uchar4*)(mrow + lk0 + 16 * j);
        char* Lb = &lds[cur][0];
        // ---- K fragments + QK^T (scores already exp2-domain) ----
        bf16x8 kf[8];
#pragma unroll
        for (int q8 = 0; q8 < 8; q8++) kf[q8] = *(const bf16x8*)(Lb + koff[q8]);
        f32x4 sacc[4];
#pragma unroll
        for (int j = 0; j < 4; j++) sacc[j] = (f32x4){0.f, 0.f, 0.f, 0.f};
#pragma unroll
        for (int j = 0; j < 4; j++) {
            sacc[j] = __builtin_amdgcn_mfma_f32_16x16x32_bf16(kf[2 * j], qf0, sacc[j], 0, 0, 0);
            sacc[j] = __builtin_amdgcn_mfma_f32_16x16x32_bf16(kf[2 * j + 1], qf1, sacc[j], 0, 0, 0);
        }
        // ---- p = exp2(s) * mask (no max subtraction); pack via v_perm ----
        unsigned W[4][2];
        float rs = 0.f;
#pragma unroll
        for (int j = 0; j < 4; j++) {
            float p0 = __builtin_amdgcn_exp2f(sacc[j][0]) * (float)mu[j].x;
            float p1 = __builtin_amdgcn_exp2f(sacc[j][1]) * (float)mu[j].y;
            float p2 = __builtin_amdgcn_exp2f(sacc[j][2]) * (float)mu[j].z;
            float p3 = __builtin_amdgcn_exp2f(sacc[j][3]) * (float)mu[j].w;
            rs += (p0 + p1) + (p2 + p3);
            W[j][0] = __builtin_amdgcn_perm(__float_as_uint(p1), __float_as_uint(p0),
                                            0x07060302u);
            W[j][1] = __builtin_amdgcn_perm(__float_as_uint(p3), __float_as_uint(p2),
                                            0x07060302u);
        }
        rs += __shfl_xor(rs, 16);
        rs += __shfl_xor(rs, 32);
        l_r += rs;
        // ---- register-only P exchange + PV (V frags per ks-half) ----
#pragma unroll
        for (int ks = 0; ks < 2; ks++) {
            bf16x8 vf[4];
#pragma unroll
            for (int jd = 0; jd < 4; jd++)
                vf[jd] = *(const bf16x8*)(Lb + voff[ks * 4 + jd]);
            unsigned a0 = __shfl((int)W[2 * ks][0], L0), b0 = __shfl((int)W[2 * ks + 1][0], L0);
            unsigned a1 = __shfl((int)W[2 * ks][1], L0), b1 = __shfl((int)W[2 * ks + 1][1], L0);
            unsigned a2 = __shfl((int)W[2 * ks][0], L1), b2 = __shfl((int)W[2 * ks + 1][0], L1);
            unsigned a3 = __shfl((int)W[2 * ks][1], L1), b3 = __shfl((int)W[2 * ks + 1][1], L1);
            u32x4 pw = (u32x4){hi ? b0 : a0, hi ? b1 : a1, hi ? b2 : a2, hi ? b3 : a3};
            bf16x8 pB = __builtin_bit_cast(bf16x8, pw);
#pragma unroll
            for (int jd = 0; jd < 4; jd++)
                oacc[jd] = __builtin_amdgcn_mfma_f32_16x16x32_bf16(vf[jd], pB,
                                                                   oacc[jd], 0, 0, 0);
        }
        // explicit drain: stage(kt+1) landed + all LDS reads complete, THEN barrier
        asm volatile("s_waitcnt vmcnt(0) lgkmcnt(0)" ::: "memory");
        __builtin_amdgcn_sched_barrier(0);
        __syncthreads();
        cur ^= 1;
    }

    const float inv = 1.0f / (l_r + 1e-20f);
    us* zp = Z + (size_t)(b * 2048 + qrow) * 1024 + h * 64 + lg * 4;
#pragma unroll
    for (int jd = 0; jd < 4; jd++) {
        us4 pk;
        pk.x = f2bf(oacc[jd][0] * inv);
        pk.y = f2bf(oacc[jd][1] * inv);
        pk.z = f2bf(oacc[jd][2] * inv);
        pk.w = f2bf(oacc[jd][3] * inv);
        *(us4*)(zp + jd * 16) = pk;
    }
}

// ---------------- launcher ----------------

extern "C" void kernel_launch(void* const* d_in, const int* in_sizes, int n_in,
                              void* d_out, int out_size, void* d_ws, size_t ws_size,
                              hipStream_t stream) {
    const float* x = (const float*)d_in[0];
    const int* mask = (const int*)d_in[1];
    const float* Wqkv = (const float*)d_in[2];
    const float* Wout = (const float*)d_in[3];
    const float* bout = (const float*)d_in[4];
    float* out = (float*)d_out;
    char* ws = (char*)d_ws;

    // 48 MB layout (proven)
    unsigned short* xz    = (unsigned short*)(ws);               // 8 MB (x bf16, later Z bf16)
    unsigned short* wqkvT = (unsigned short*)(ws + (8u << 20));  // 6 MB
    unsigned short* woutT = (unsigned short*)(ws + (14u << 20)); // 2 MB
    unsigned char*  m8    = (unsigned char*)(ws + (16u << 20));  // 8 MB
    unsigned short* Qb    = (unsigned short*)(ws + (24u << 20)); // 8 MB
    unsigned short* Kb    = (unsigned short*)(ws + (32u << 20)); // 8 MB
    unsigned short* VTb   = (unsigned short*)(ws + (40u << 20)); // 8 MB

    prep<<<12288, 256, 0, stream>>>(x, xz, mask, (unsigned int*)m8);
    transposew2<<<dim3(128, 32), 256, 0, stream>>>(Wqkv, wqkvT, Wout, woutT);
    gemm_bf16<0><<<dim3(3072 / 128, 4096 / 128), 256, 0, stream>>>(
        xz, wqkvT, 4096, 3072, 1024, Qb, Kb, VTb, nullptr, nullptr);
    flash_attn<<<dim3(16, 32), 512, 0, stream>>>(Qb, Kb, VTb, m8, xz);
    gemm_bf16<1><<<dim3(1024 / 128, 4096 / 128), 256, 0, stream>>>(
        xz, woutT, 4096, 1024, 1024, nullptr, nullptr, nullptr, bout, out);
}

// Round 23
// 145.280 us; speedup vs baseline: 1.1854x; 1.0996x over previous
//
#include <hip/hip_runtime.h>

typedef __attribute__((ext_vector_type(8))) short bf16x8;
typedef __attribute__((ext_vector_type(4))) float f32x4;
typedef __attribute__((ext_vector_type(4))) unsigned short us4;
typedef __attribute__((ext_vector_type(4))) unsigned int u32x4;
typedef unsigned short us;

#define C2 0.18033688011112042f  /* SCALE * log2(e): Q pre-scale -> exp2-domain scores */

__device__ __forceinline__ unsigned short f2bf(float f) {
    unsigned int u = __float_as_uint(f);
    u = (u + 0x7FFF + ((u >> 16) & 1)) >> 16;   // RNE
    return (unsigned short)u;
}

// ---------------- prep kernels (merged dispatches; bodies proven) ----------

// blocks [0,4096): x fp32 -> bf16.  blocks [4096,12288): mask int32 -> bytes.
__global__ __launch_bounds__(256) void prep(const float* __restrict__ X,
                                            unsigned short* __restrict__ O,
                                            const int* __restrict__ Mi,
                                            unsigned int* __restrict__ Mo) {
    int bx = blockIdx.x;
    if (bx < 4096) {
        int i = bx * 256 + threadIdx.x;
        float4 v = ((const float4*)X)[i];
        us4 o;
        o.x = f2bf(v.x); o.y = f2bf(v.y); o.z = f2bf(v.z); o.w = f2bf(v.w);
        ((us4*)O)[i] = o;
    } else {
        int i = (bx - 4096) * 256 + threadIdx.x;
        int4 v = ((const int4*)Mi)[i];
        Mo[i] = (unsigned)(v.x & 1) | ((unsigned)(v.y & 1) << 8) |
                ((unsigned)(v.z & 1) << 16) | ((unsigned)(v.w & 1) << 24);
    }
}

// W [Kd][Cd] fp32 -> WT [Cd][Kd] bf16; two weight matrices in one launch.
__global__ __launch_bounds__(256) void transposew2(const float* __restrict__ W0,
                                                   unsigned short* __restrict__ WT0,
                                                   const float* __restrict__ W1,
                                                   unsigned short* __restrict__ WT1) {
    const float* W; unsigned short* WT; int Cd; int bx = blockIdx.x;
    if (bx < 96) { W = W0; WT = WT0; Cd = 3072; }
    else         { W = W1; WT = WT1; Cd = 1024; bx -= 96; }
    const int Kd = 1024;
    __shared__ float t[32][33];
    int c0 = bx * 32, k0 = blockIdx.y * 32;
    int tx = threadIdx.x & 31, ty = threadIdx.x >> 5;  // ty 0..7
#pragma unroll
    for (int i = 0; i < 32; i += 8)
        t[ty + i][tx] = W[(size_t)(k0 + ty + i) * Cd + c0 + tx];
    __syncthreads();
#pragma unroll
    for (int i = 0; i < 32; i += 8)
        WT[(size_t)(c0 + ty + i) * Kd + k0 + tx] = f2bf(t[tx][ty + i]);
}

// ---------------- GEMM: C = A[M][K] * BT[N][K]^T ----------------
// R14/R15-proven structure, generalized tile height BM (template).
// BM=256 (512 thr, 48KB LDS) for QKV: stages 48KB per 4.2 MFLOP vs 32KB per
// 2.1 MFLOP at BM=128 -> 25% fewer staged bytes/FLOP + half the B-panel
// L2 re-fetches (R18's flash lesson transferred). BM=128 for the out-GEMM
// (small grid needs the block count). Wave formulas unchanged (wr=w>>1
// spans BM/64 rows, wc=w&1).
template <int MODE, int BM>
__global__ __launch_bounds__(BM * 2) void gemm_bf16(
    const unsigned short* __restrict__ A, const unsigned short* __restrict__ BT,
    int M, int N, int K,
    unsigned short* __restrict__ Qo, unsigned short* __restrict__ Ko,
    unsigned short* __restrict__ Vo,
    const float* __restrict__ bias, float* __restrict__ Co) {
    constexpr int NT = BM * 2;           // threads per block
    __shared__ unsigned short Asub[BM * 64];
    __shared__ unsigned short Bsub[128 * 64];
    const int bm = blockIdx.y, bn = blockIdx.x;
    const int tid = threadIdx.x, w = tid >> 6, lane = tid & 63;
    const int wr = w >> 1, wc = w & 1, l16 = lane & 15, lg = lane >> 4;

    f32x4 acc[4][4];
#pragma unroll
    for (int i = 0; i < 4; i++)
#pragma unroll
        for (int j = 0; j < 4; j++) acc[i][j] = (f32x4){0.f, 0.f, 0.f, 0.f};

    const int wbase = (tid & ~63) * 16;  // wave-uniform LDS offset

    const int nkt = K / 64;
    for (int kt = 0; kt < nkt; kt++) {
        const int k0 = kt * 64;
        // A tile: BM*8 slots of 16B; (BM*8)/NT = 4 iters at both BM
#pragma unroll
        for (int i = 0; i < (BM * 8) / NT; i++) {
            int slot = i * NT + tid;
            int r = slot >> 3, blk = slot & 7;
            const us* srcA = A + (size_t)(bm * BM + r) * K + k0 + ((blk ^ (r & 7)) << 3);
            __builtin_amdgcn_global_load_lds(
                (const __attribute__((address_space(1))) unsigned*)srcA,
                (__attribute__((address_space(3))) unsigned*)((char*)Asub + i * (NT * 16) + wbase),
                16, 0, 0);
        }
        // B tile: 1024 slots; 1024/NT iters
#pragma unroll
        for (int i = 0; i < 1024 / NT; i++) {
            int slot = i * NT + tid;
            int r = slot >> 3, blk = slot & 7;
            const us* srcB = BT + (size_t)(bn * 128 + r) * K + k0 + ((blk ^ (r & 7)) << 3);
            __builtin_amdgcn_global_load_lds(
                (const __attribute__((address_space(1))) unsigned*)srcB,
                (__attribute__((address_space(3))) unsigned*)((char*)Bsub + i * (NT * 16) + wbase),
                16, 0, 0);
        }
        asm volatile("s_waitcnt vmcnt(0)" ::: "memory");
        __builtin_amdgcn_sched_barrier(0);
        __syncthreads();
#pragma unroll
        for (int ks = 0; ks < 2; ks++) {
            bf16x8 af[4], bfr[4];
            int kk = ks * 32 + lg * 8;
#pragma unroll
            for (int i = 0; i < 4; i++) {
                int r = wr * 64 + i * 16 + l16;
                af[i] = *(bf16x8*)((char*)Asub + ((r * 128 + kk * 2) ^ ((r & 7) << 4)));
                int c = wc * 64 + i * 16 + l16;
                bfr[i] = *(bf16x8*)((char*)Bsub + ((c * 128 + kk * 2) ^ ((c & 7) << 4)));
            }
#pragma unroll
            for (int i = 0; i < 4; i++)
#pragma unroll
                for (int j = 0; j < 4; j++)
                    acc[i][j] = __builtin_amdgcn_mfma_f32_16x16x32_bf16(
                        af[i], bfr[j], acc[i][j], 0, 0, 0);
        }
        __syncthreads();
    }

    if (MODE == 0) {
#pragma unroll
        for (int i = 0; i < 4; i++) {
            int grow = bm * BM + wr * 64 + i * 16 + lg * 4;
            int bb = grow >> 11, ll = grow & 2047;
#pragma unroll
            for (int j = 0; j < 4; j++) {
                int gcol = bn * 128 + wc * 64 + j * 16 + l16;
                int s = gcol >> 10, hh = (gcol >> 6) & 15, dd = gcol & 63;
                int bhh = bb * 16 + hh;
                if (s == 2) {
                    us4 pk;
                    pk.x = f2bf(acc[i][j][0]); pk.y = f2bf(acc[i][j][1]);
                    pk.z = f2bf(acc[i][j][2]); pk.w = f2bf(acc[i][j][3]);
                    *(us4*)(Vo + (size_t)(bhh * 64 + dd) * 2048 + ll) = pk;
                } else if (s == 0) {
                    // Q: pre-scale by C2 so QK^T lands in exp2 domain
                    unsigned short* dst = Qo + (size_t)(bhh * 2048 + ll) * 64 + dd;
#pragma unroll
                    for (int r = 0; r < 4; r++)
                        dst[(size_t)r * 64] = f2bf(acc[i][j][r] * C2);
                } else {
                    unsigned short* dst = Ko + (size_t)(bhh * 2048 + ll) * 64 + dd;
#pragma unroll
                    for (int r = 0; r < 4; r++) dst[(size_t)r * 64] = f2bf(acc[i][j][r]);
                }
            }
        }
    } else {
#pragma unroll
        for (int i = 0; i < 4; i++) {
            int grow = bm * BM + wr * 64 + i * 16 + lg * 4;
#pragma unroll
            for (int j = 0; j < 4; j++) {
                int gcol = bn * 128 + wc * 64 + j * 16 + l16;
                float bv = bias[gcol];
#pragma unroll
                for (int r = 0; r < 4; r++)
                    Co[(size_t)(grow + r) * N + gcol] = acc[i][j][r] + bv;
            }
        }
    }
}

// ---------------- flash attention (8-wave, no-max softmax) ------------------
// EXACT R19/R22 body (best verified: 80.5 us flash; passed pre+post twice).
__global__ __launch_bounds__(512, 4) void flash_attn(
    const us* __restrict__ Q, const us* __restrict__ Kt,
    const us* __restrict__ VT, const unsigned char* __restrict__ M8,
    us* __restrict__ Z) {
    __shared__ char lds[2][16384];   // per buf: K 0..8191, VT 8192..16383
    const int bh = blockIdx.y;
    const int b = bh >> 4, h = bh & 15;
    const int tid = threadIdx.x, w = tid >> 6, lane = tid & 63;
    const int l16 = lane & 15, lg = lane >> 4;
    const int qb0 = blockIdx.x * 128;
    const int qrow = qb0 + w * 16 + l16;

    const size_t kbh = (size_t)bh * 2048;
    const size_t vbh = (size_t)bh * 64;

    const us* Qp = Q + (size_t)(kbh + qrow) * 64 + lg * 8;
    bf16x8 qf0 = *(const bf16x8*)(Qp);
    bf16x8 qf1 = *(const bf16x8*)(Qp + 32);

    float l_r = 0.f;
    f32x4 oacc[4];
#pragma unroll
    for (int jd = 0; jd < 4; jd++) oacc[jd] = (f32x4){0.f, 0.f, 0.f, 0.f};

    // exchange source lanes (loop-invariant)
    const int L0 = l16 + (((2 * lg) & 3) << 4);
    const int L1 = l16 + (((2 * lg + 1) & 3) << 4);
    const bool hi = (lg >> 1) != 0;

    // loop-invariant LDS read offsets (swizzled)
    int koff[8], voff[8];
#pragma unroll
    for (int j = 0; j < 4; j++)
#pragma unroll
        for (int hh = 0; hh < 2; hh++)
            koff[2 * j + hh] = (16 * j + l16) * 128 + ((64 * hh + 16 * lg) ^ ((l16 & 7) << 4));
#pragma unroll
    for (int ks = 0; ks < 2; ks++)
#pragma unroll
        for (int jd = 0; jd < 4; jd++)
            voff[ks * 4 + jd] =
                8192 + (jd * 16 + l16) * 128 + ((64 * ks + 16 * lg) ^ ((l16 & 7) << 4));

    // this lane's q-row mask bytes; per (kt,j): 4 consecutive keys 16j+4lg+r
    const unsigned char* mrow = M8 + (size_t)(b * 2048 + qrow) * 2048 + 4 * lg;

    const int wbase = (tid & ~63) * 16;  // wave-uniform LDS offset (w*1024)

    // 512 threads: K tile = 512 slots (1/thread), V tile = 512 slots (1/thread)
    auto STAGE = [&](int bufi, int kt) {
        char* base = &lds[bufi][0];
        const int lk = kt * 64;
        {
            int r = tid >> 3, blk = tid & 7;
            const us* src = Kt + (kbh + lk + r) * 64 + ((blk ^ (r & 7)) << 3);
            __builtin_amdgcn_global_load_lds(
                (const __attribute__((address_space(1))) unsigned*)src,
                (__attribute__((address_space(3))) unsigned*)(base + wbase),
                16, 0, 0);
        }
        {
            int r = tid >> 3, blk = tid & 7;
            const us* src = VT + (vbh + r) * 2048 + lk + ((blk ^ (r & 7)) << 3);
            __builtin_amdgcn_global_load_lds(
                (const __attribute__((address_space(1))) unsigned*)src,
                (__attribute__((address_space(3))) unsigned*)(base + 8192 + wbase),
                16, 0, 0);
        }
    };

    STAGE(0, 0);
    asm volatile("s_waitcnt vmcnt(0) lgkmcnt(0)" ::: "memory");
    __builtin_amdgcn_sched_barrier(0);
    __syncthreads();
    int cur = 0;

    for (int kt = 0; kt < 32; kt++) {
        const int lk0 = kt * 64;
        if (kt < 31) STAGE(cur ^ 1, kt + 1);   // issue next tile; drained at barrier below
        // ---- mask bytes for this iter: direct global (hidden under QK^T) ----
        uchar4 mu[4];
#pragma unroll
        for (int j = 0; j < 4; j++)
            mu[j] = *(const uchar4*)(mrow + lk0 + 16 * j);
        char* Lb = &lds[cur][0];
        // ---- K fragments + QK^T (scores already exp2-domain) ----
        bf16x8 kf[8];
#pragma unroll
        for (int q8 = 0; q8 < 8; q8++) kf[q8] = *(const bf16x8*)(Lb + koff[q8]);
        f32x4 sacc[4];
#pragma unroll
        for (int j = 0; j < 4; j++) sacc[j] = (f32x4){0.f, 0.f, 0.f, 0.f};
#pragma unroll
        for (int j = 0; j < 4; j++) {
            sacc[j] = __builtin_amdgcn_mfma_f32_16x16x32_bf16(kf[2 * j], qf0, sacc[j], 0, 0, 0);
            sacc[j] = __builtin_amdgcn_mfma_f32_16x16x32_bf16(kf[2 * j + 1], qf1, sacc[j], 0, 0, 0);
        }
        // ---- p = exp2(s) * mask (no max subtraction); pack via v_perm ----
        unsigned W[4][2];
        float rs = 0.f;
#pragma unroll
        for (int j = 0; j < 4; j++) {
            float p0 = __builtin_amdgcn_exp2f(sacc[j][0]) * (float)mu[j].x;
            float p1 = __builtin_amdgcn_exp2f(sacc[j][1]) * (float)mu[j].y;
            float p2 = __builtin_amdgcn_exp2f(sacc[j][2]) * (float)mu[j].z;
            float p3 = __builtin_amdgcn_exp2f(sacc[j][3]) * (float)mu[j].w;
            rs += (p0 + p1) + (p2 + p3);
            W[j][0] = __builtin_amdgcn_perm(__float_as_uint(p1), __float_as_uint(p0),
                                            0x07060302u);
            W[j][1] = __builtin_amdgcn_perm(__float_as_uint(p3), __float_as_uint(p2),
                                            0x07060302u);
        }
        rs += __shfl_xor(rs, 16);
        rs += __shfl_xor(rs, 32);
        l_r += rs;
        // ---- register-only P exchange + PV (V frags per ks-half) ----
#pragma unroll
        for (int ks = 0; ks < 2; ks++) {
            bf16x8 vf[4];
#pragma unroll
            for (int jd = 0; jd < 4; jd++)
                vf[jd] = *(const bf16x8*)(Lb + voff[ks * 4 + jd]);
            unsigned a0 = __shfl((int)W[2 * ks][0], L0), b0 = __shfl((int)W[2 * ks + 1][0], L0);
            unsigned a1 = __shfl((int)W[2 * ks][1], L0), b1 = __shfl((int)W[2 * ks + 1][1], L0);
            unsigned a2 = __shfl((int)W[2 * ks][0], L1), b2 = __shfl((int)W[2 * ks + 1][0], L1);
            unsigned a3 = __shfl((int)W[2 * ks][1], L1), b3 = __shfl((int)W[2 * ks + 1][1], L1);
            u32x4 pw = (u32x4){hi ? b0 : a0, hi ? b1 : a1, hi ? b2 : a2, hi ? b3 : a3};
            bf16x8 pB = __builtin_bit_cast(bf16x8, pw);
#pragma unroll
            for (int jd = 0; jd < 4; jd++)
                oacc[jd] = __builtin_amdgcn_mfma_f32_16x16x32_bf16(vf[jd], pB,
                                                                   oacc[jd], 0, 0, 0);
        }
        // explicit drain: stage(kt+1) landed + all LDS reads complete, THEN barrier
        asm volatile("s_waitcnt vmcnt(0) lgkmcnt(0)" ::: "memory");
        __builtin_amdgcn_sched_barrier(0);
        __syncthreads();
        cur ^= 1;
    }

    const float inv = 1.0f / (l_r + 1e-20f);
    us* zp = Z + (size_t)(b * 2048 + qrow) * 1024 + h * 64 + lg * 4;
#pragma unroll
    for (int jd = 0; jd < 4; jd++) {
        us4 pk;
        pk.x = f2bf(oacc[jd][0] * inv);
        pk.y = f2bf(oacc[jd][1] * inv);
        pk.z = f2bf(oacc[jd][2] * inv);
        pk.w = f2bf(oacc[jd][3] * inv);
        *(us4*)(zp + jd * 16) = pk;
    }
}

// ---------------- launcher ----------------

extern "C" void kernel_launch(void* const* d_in, const int* in_sizes, int n_in,
                              void* d_out, int out_size, void* d_ws, size_t ws_size,
                              hipStream_t stream) {
    const float* x = (const float*)d_in[0];
    const int* mask = (const int*)d_in[1];
    const float* Wqkv = (const float*)d_in[2];
    const float* Wout = (const float*)d_in[3];
    const float* bout = (const float*)d_in[4];
    float* out = (float*)d_out;
    char* ws = (char*)d_ws;

    // 48 MB layout (proven)
    unsigned short* xz    = (unsigned short*)(ws);               // 8 MB (x bf16, later Z bf16)
    unsigned short* wqkvT = (unsigned short*)(ws + (8u << 20));  // 6 MB
    unsigned short* woutT = (unsigned short*)(ws + (14u << 20)); // 2 MB
    unsigned char*  m8    = (unsigned char*)(ws + (16u << 20));  // 8 MB
    unsigned short* Qb    = (unsigned short*)(ws + (24u << 20)); // 8 MB
    unsigned short* Kb    = (unsigned short*)(ws + (32u << 20)); // 8 MB
    unsigned short* VTb   = (unsigned short*)(ws + (40u << 20)); // 8 MB

    prep<<<12288, 256, 0, stream>>>(x, xz, mask, (unsigned int*)m8);
    transposew2<<<dim3(128, 32), 256, 0, stream>>>(Wqkv, wqkvT, Wout, woutT);
    gemm_bf16<0, 256><<<dim3(3072 / 128, 4096 / 256), 512, 0, stream>>>(
        xz, wqkvT, 4096, 3072, 1024, Qb, Kb, VTb, nullptr, nullptr);
    flash_attn<<<dim3(16, 32), 512, 0, stream>>>(Qb, Kb, VTb, m8, xz);
    gemm_bf16<1, 128><<<dim3(1024 / 128, 4096 / 128), 256, 0, stream>>>(
        xz, woutT, 4096, 1024, 1024, nullptr, nullptr, nullptr, bout, out);
}

// Round 24
// 143.101 us; speedup vs baseline: 1.2034x; 1.0152x over previous
//
#include <hip/hip_runtime.h>

typedef __attribute__((ext_vector_type(8))) short bf16x8;
typedef __attribute__((ext_vector_type(4))) float f32x4;
typedef __attribute__((ext_vector_type(4))) unsigned short us4;
typedef __attribute__((ext_vector_type(4))) unsigned int u32x4;
typedef unsigned short us;

#define C2 0.18033688011112042f  /* SCALE * log2(e): Q pre-scale -> exp2-domain scores */

__device__ __forceinline__ unsigned short f2bf(float f) {
    unsigned int u = __float_as_uint(f);
    u = (u + 0x7FFF + ((u >> 16) & 1)) >> 16;   // RNE
    return (unsigned short)u;
}

// ---------------- prep kernel (all element-wise + transpose prep, 1 launch) -
// blocks [0,4096):      x fp32 -> bf16
// blocks [4096,12288):  mask int32 -> bytes
// blocks [12288,16384): W transposes (Wqkv then Wout), 32x32 tiles
__global__ __launch_bounds__(256) void prep(const float* __restrict__ X,
                                            unsigned short* __restrict__ O,
                                            const int* __restrict__ Mi,
                                            unsigned int* __restrict__ Mo,
                                            const float* __restrict__ W0,
                                            unsigned short* __restrict__ WT0,
                                            const float* __restrict__ W1,
                                            unsigned short* __restrict__ WT1) {
    __shared__ float t[32][33];
    int bx = blockIdx.x;
    if (bx < 4096) {
        int i = bx * 256 + threadIdx.x;
        float4 v = ((const float4*)X)[i];
        us4 o;
        o.x = f2bf(v.x); o.y = f2bf(v.y); o.z = f2bf(v.z); o.w = f2bf(v.w);
        ((us4*)O)[i] = o;
    } else if (bx < 12288) {
        int i = (bx - 4096) * 256 + threadIdx.x;
        int4 v = ((const int4*)Mi)[i];
        Mo[i] = (unsigned)(v.x & 1) | ((unsigned)(v.y & 1) << 8) |
                ((unsigned)(v.z & 1) << 16) | ((unsigned)(v.w & 1) << 24);
    } else {
        int tw = bx - 12288;
        int cb = tw & 127, kb = tw >> 7;    // c-block [0,128), k-block [0,32)
        const float* W; unsigned short* WT; int Cd;
        if (cb < 96) { W = W0; WT = WT0; Cd = 3072; }
        else         { W = W1; WT = WT1; Cd = 1024; cb -= 96; }
        const int Kd = 1024;
        int c0 = cb * 32, k0 = kb * 32;
        int tx = threadIdx.x & 31, ty = threadIdx.x >> 5;  // ty 0..7
#pragma unroll
        for (int i = 0; i < 32; i += 8)
            t[ty + i][tx] = W[(size_t)(k0 + ty + i) * Cd + c0 + tx];
        __syncthreads();
#pragma unroll
        for (int i = 0; i < 32; i += 8)
            WT[(size_t)(c0 + ty + i) * Kd + k0 + tx] = f2bf(t[tx][ty + i]);
    }
}

// ---------------- GEMM: C = A[M][K] * BT[N][K]^T ----------------
// R14/R15-proven structure, generalized tile height BM. BM=256 (512 thr,
// 48KB LDS) for QKV (R23: -14 us); BM=128 for the out-GEMM (needs blocks).
template <int MODE, int BM>
__global__ __launch_bounds__(BM * 2) void gemm_bf16(
    const unsigned short* __restrict__ A, const unsigned short* __restrict__ BT,
    int M, int N, int K,
    unsigned short* __restrict__ Qo, unsigned short* __restrict__ Ko,
    unsigned short* __restrict__ Vo,
    const float* __restrict__ bias, float* __restrict__ Co) {
    constexpr int NT = BM * 2;           // threads per block
    __shared__ unsigned short Asub[BM * 64];
    __shared__ unsigned short Bsub[128 * 64];
    const int bm = blockIdx.y, bn = blockIdx.x;
    const int tid = threadIdx.x, w = tid >> 6, lane = tid & 63;
    const int wr = w >> 1, wc = w & 1, l16 = lane & 15, lg = lane >> 4;

    f32x4 acc[4][4];
#pragma unroll
    for (int i = 0; i < 4; i++)
#pragma unroll
        for (int j = 0; j < 4; j++) acc[i][j] = (f32x4){0.f, 0.f, 0.f, 0.f};

    const int wbase = (tid & ~63) * 16;  // wave-uniform LDS offset

    const int nkt = K / 64;
    for (int kt = 0; kt < nkt; kt++) {
        const int k0 = kt * 64;
#pragma unroll
        for (int i = 0; i < (BM * 8) / NT; i++) {
            int slot = i * NT + tid;
            int r = slot >> 3, blk = slot & 7;
            const us* srcA = A + (size_t)(bm * BM + r) * K + k0 + ((blk ^ (r & 7)) << 3);
            __builtin_amdgcn_global_load_lds(
                (const __attribute__((address_space(1))) unsigned*)srcA,
                (__attribute__((address_space(3))) unsigned*)((char*)Asub + i * (NT * 16) + wbase),
                16, 0, 0);
        }
#pragma unroll
        for (int i = 0; i < 1024 / NT; i++) {
            int slot = i * NT + tid;
            int r = slot >> 3, blk = slot & 7;
            const us* srcB = BT + (size_t)(bn * 128 + r) * K + k0 + ((blk ^ (r & 7)) << 3);
            __builtin_amdgcn_global_load_lds(
                (const __attribute__((address_space(1))) unsigned*)srcB,
                (__attribute__((address_space(3))) unsigned*)((char*)Bsub + i * (NT * 16) + wbase),
                16, 0, 0);
        }
        asm volatile("s_waitcnt vmcnt(0)" ::: "memory");
        __builtin_amdgcn_sched_barrier(0);
        __syncthreads();
#pragma unroll
        for (int ks = 0; ks < 2; ks++) {
            bf16x8 af[4], bfr[4];
            int kk = ks * 32 + lg * 8;
#pragma unroll
            for (int i = 0; i < 4; i++) {
                int r = wr * 64 + i * 16 + l16;
                af[i] = *(bf16x8*)((char*)Asub + ((r * 128 + kk * 2) ^ ((r & 7) << 4)));
                int c = wc * 64 + i * 16 + l16;
                bfr[i] = *(bf16x8*)((char*)Bsub + ((c * 128 + kk * 2) ^ ((c & 7) << 4)));
            }
#pragma unroll
            for (int i = 0; i < 4; i++)
#pragma unroll
                for (int j = 0; j < 4; j++)
                    acc[i][j] = __builtin_amdgcn_mfma_f32_16x16x32_bf16(
                        af[i], bfr[j], acc[i][j], 0, 0, 0);
        }
        __syncthreads();
    }

    if (MODE == 0) {
#pragma unroll
        for (int i = 0; i < 4; i++) {
            int grow = bm * BM + wr * 64 + i * 16 + lg * 4;
            int bb = grow >> 11, ll = grow & 2047;
#pragma unroll
            for (int j = 0; j < 4; j++) {
                int gcol = bn * 128 + wc * 64 + j * 16 + l16;
                int s = gcol >> 10, hh = (gcol >> 6) & 15, dd = gcol & 63;
                int bhh = bb * 16 + hh;
                if (s == 2) {
                    us4 pk;
                    pk.x = f2bf(acc[i][j][0]); pk.y = f2bf(acc[i][j][1]);
                    pk.z = f2bf(acc[i][j][2]); pk.w = f2bf(acc[i][j][3]);
                    *(us4*)(Vo + (size_t)(bhh * 64 + dd) * 2048 + ll) = pk;
                } else if (s == 0) {
                    // Q: pre-scale by C2 so QK^T lands in exp2 domain
                    unsigned short* dst = Qo + (size_t)(bhh * 2048 + ll) * 64 + dd;
#pragma unroll
                    for (int r = 0; r < 4; r++)
                        dst[(size_t)r * 64] = f2bf(acc[i][j][r] * C2);
                } else {
                    unsigned short* dst = Ko + (size_t)(bhh * 2048 + ll) * 64 + dd;
#pragma unroll
                    for (int r = 0; r < 4; r++) dst[(size_t)r * 64] = f2bf(acc[i][j][r]);
                }
            }
        }
    } else {
#pragma unroll
        for (int i = 0; i < 4; i++) {
            int grow = bm * BM + wr * 64 + i * 16 + lg * 4;
#pragma unroll
            for (int j = 0; j < 4; j++) {
                int gcol = bn * 128 + wc * 64 + j * 16 + l16;
                float bv = bias[gcol];
#pragma unroll
                for (int r = 0; r < 4; r++)
                    Co[(size_t)(grow + r) * N + gcol] = acc[i][j][r] + bv;
            }
        }
    }
}

// ---------------- flash attention (8-wave, no-max softmax) ------------------
// EXACT R19/R22/R23 body (best verified: ~81 us; passed pre+post 3x).
__global__ __launch_bounds__(512, 4) void flash_attn(
    const us* __restrict__ Q, const us* __restrict__ Kt,
    const us* __restrict__ VT, const unsigned char* __restrict__ M8,
    us* __restrict__ Z) {
    __shared__ char lds[2][16384];   // per buf: K 0..8191, VT 8192..16383
    const int bh = blockIdx.y;
    const int b = bh >> 4, h = bh & 15;
    const int tid = threadIdx.x, w = tid >> 6, lane = tid & 63;
    const int l16 = lane & 15, lg = lane >> 4;
    const int qb0 = blockIdx.x * 128;
    const int qrow = qb0 + w * 16 + l16;

    const size_t kbh = (size_t)bh * 2048;
    const size_t vbh = (size_t)bh * 64;

    const us* Qp = Q + (size_t)(kbh + qrow) * 64 + lg * 8;
    bf16x8 qf0 = *(const bf16x8*)(Qp);
    bf16x8 qf1 = *(const bf16x8*)(Qp + 32);

    float l_r = 0.f;
    f32x4 oacc[4];
#pragma unroll
    for (int jd = 0; jd < 4; jd++) oacc[jd] = (f32x4){0.f, 0.f, 0.f, 0.f};

    // exchange source lanes (loop-invariant)
    const int L0 = l16 + (((2 * lg) & 3) << 4);
    const int L1 = l16 + (((2 * lg + 1) & 3) << 4);
    const bool hi = (lg >> 1) != 0;

    // loop-invariant LDS read offsets (swizzled)
    int koff[8], voff[8];
#pragma unroll
    for (int j = 0; j < 4; j++)
#pragma unroll
        for (int hh = 0; hh < 2; hh++)
            koff[2 * j + hh] = (16 * j + l16) * 128 + ((64 * hh + 16 * lg) ^ ((l16 & 7) << 4));
#pragma unroll
    for (int ks = 0; ks < 2; ks++)
#pragma unroll
        for (int jd = 0; jd < 4; jd++)
            voff[ks * 4 + jd] =
                8192 + (jd * 16 + l16) * 128 + ((64 * ks + 16 * lg) ^ ((l16 & 7) << 4));

    // this lane's q-row mask bytes; per (kt,j): 4 consecutive keys 16j+4lg+r
    const unsigned char* mrow = M8 + (size_t)(b * 2048 + qrow) * 2048 + 4 * lg;

    const int wbase = (tid & ~63) * 16;  // wave-uniform LDS offset (w*1024)

    // 512 threads: K tile = 512 slots (1/thread), V tile = 512 slots (1/thread)
    auto STAGE = [&](int bufi, int kt) {
        char* base = &lds[bufi][0];
        const int lk = kt * 64;
        {
            int r = tid >> 3, blk = tid & 7;
            const us* src = Kt + (kbh + lk + r) * 64 + ((blk ^ (r & 7)) << 3);
            __builtin_amdgcn_global_load_lds(
                (const __attribute__((address_space(1))) unsigned*)src,
                (__attribute__((address_space(3))) unsigned*)(base + wbase),
                16, 0, 0);
        }
        {
            int r = tid >> 3, blk = tid & 7;
            const us* src = VT + (vbh + r) * 2048 + lk + ((blk ^ (r & 7)) << 3);
            __builtin_amdgcn_global_load_lds(
                (const __attribute__((address_space(1))) unsigned*)src,
                (__attribute__((address_space(3))) unsigned*)(base + 8192 + wbase),
                16, 0, 0);
        }
    };

    STAGE(0, 0);
    asm volatile("s_waitcnt vmcnt(0) lgkmcnt(0)" ::: "memory");
    __builtin_amdgcn_sched_barrier(0);
    __syncthreads();
    int cur = 0;

    for (int kt = 0; kt < 32; kt++) {
        const int lk0 = kt * 64;
        if (kt < 31) STAGE(cur ^ 1, kt + 1);   // issue next tile; drained at barrier below
        // ---- mask bytes for this iter: direct global (hidden under QK^T) ----
        uchar4 mu[4];
#pragma unroll
        for (int j = 0; j < 4; j++)
            mu[j] = *(const uchar4*)(mrow + lk0 + 16 * j);
        char* Lb = &lds[cur][0];
        // ---- K fragments + QK^T (scores already exp2-domain) ----
        bf16x8 kf[8];
#pragma unroll
        for (int q8 = 0; q8 < 8; q8++) kf[q8] = *(const bf16x8*)(Lb + koff[q8]);
        f32x4 sacc[4];
#pragma unroll
        for (int j = 0; j < 4; j++) sacc[j] = (f32x4){0.f, 0.f, 0.f, 0.f};
#pragma unroll
        for (int j = 0; j < 4; j++) {
            sacc[j] = __builtin_amdgcn_mfma_f32_16x16x32_bf16(kf[2 * j], qf0, sacc[j], 0, 0, 0);
            sacc[j] = __builtin_amdgcn_mfma_f32_16x16x32_bf16(kf[2 * j + 1], qf1, sacc[j], 0, 0, 0);
        }
        // ---- p = exp2(s) * mask (no max subtraction); pack via v_perm ----
        unsigned W[4][2];
        float rs = 0.f;
#pragma unroll
        for (int j = 0; j < 4; j++) {
            float p0 = __builtin_amdgcn_exp2f(sacc[j][0]) * (float)mu[j].x;
            float p1 = __builtin_amdgcn_exp2f(sacc[j][1]) * (float)mu[j].y;
            float p2 = __builtin_amdgcn_exp2f(sacc[j][2]) * (float)mu[j].z;
            float p3 = __builtin_amdgcn_exp2f(sacc[j][3]) * (float)mu[j].w;
            rs += (p0 + p1) + (p2 + p3);
            W[j][0] = __builtin_amdgcn_perm(__float_as_uint(p1), __float_as_uint(p0),
                                            0x07060302u);
            W[j][1] = __builtin_amdgcn_perm(__float_as_uint(p3), __float_as_uint(p2),
                                            0x07060302u);
        }
        rs += __shfl_xor(rs, 16);
        rs += __shfl_xor(rs, 32);
        l_r += rs;
        // ---- register-only P exchange + PV (V frags per ks-half) ----
#pragma unroll
        for (int ks = 0; ks < 2; ks++) {
            bf16x8 vf[4];
#pragma unroll
            for (int jd = 0; jd < 4; jd++)
                vf[jd] = *(const bf16x8*)(Lb + voff[ks * 4 + jd]);
            unsigned a0 = __shfl((int)W[2 * ks][0], L0), b0 = __shfl((int)W[2 * ks + 1][0], L0);
            unsigned a1 = __shfl((int)W[2 * ks][1], L0), b1 = __shfl((int)W[2 * ks + 1][1], L0);
            unsigned a2 = __shfl((int)W[2 * ks][0], L1), b2 = __shfl((int)W[2 * ks + 1][0], L1);
            unsigned a3 = __shfl((int)W[2 * ks][1], L1), b3 = __shfl((int)W[2 * ks + 1][1], L1);
            u32x4 pw = (u32x4){hi ? b0 : a0, hi ? b1 : a1, hi ? b2 : a2, hi ? b3 : a3};
            bf16x8 pB = __builtin_bit_cast(bf16x8, pw);
#pragma unroll
            for (int jd = 0; jd < 4; jd++)
                oacc[jd] = __builtin_amdgcn_mfma_f32_16x16x32_bf16(vf[jd], pB,
                                                                   oacc[jd], 0, 0, 0);
        }
        // explicit drain: stage(kt+1) landed + all LDS reads complete, THEN barrier
        asm volatile("s_waitcnt vmcnt(0) lgkmcnt(0)" ::: "memory");
        __builtin_amdgcn_sched_barrier(0);
        __syncthreads();
        cur ^= 1;
    }

    const float inv = 1.0f / (l_r + 1e-20f);
    us* zp = Z + (size_t)(b * 2048 + qrow) * 1024 + h * 64 + lg * 4;
#pragma unroll
    for (int jd = 0; jd < 4; jd++) {
        us4 pk;
        pk.x = f2bf(oacc[jd][0] * inv);
        pk.y = f2bf(oacc[jd][1] * inv);
        pk.z = f2bf(oacc[jd][2] * inv);
        pk.w = f2bf(oacc[jd][3] * inv);
        *(us4*)(zp + jd * 16) = pk;
    }
}

// ---------------- launcher ----------------

extern "C" void kernel_launch(void* const* d_in, const int* in_sizes, int n_in,
                              void* d_out, int out_size, void* d_ws, size_t ws_size,
                              hipStream_t stream) {
    const float* x = (const float*)d_in[0];
    const int* mask = (const int*)d_in[1];
    const float* Wqkv = (const float*)d_in[2];
    const float* Wout = (const float*)d_in[3];
    const float* bout = (const float*)d_in[4];
    float* out = (float*)d_out;
    char* ws = (char*)d_ws;

    // 48 MB layout (proven)
    unsigned short* xz    = (unsigned short*)(ws);               // 8 MB (x bf16, later Z bf16)
    unsigned short* wqkvT = (unsigned short*)(ws + (8u << 20));  // 6 MB
    unsigned short* woutT = (unsigned short*)(ws + (14u << 20)); // 2 MB
    unsigned char*  m8    = (unsigned char*)(ws + (16u << 20));  // 8 MB
    unsigned short* Qb    = (unsigned short*)(ws + (24u << 20)); // 8 MB
    unsigned short* Kb    = (unsigned short*)(ws + (32u << 20)); // 8 MB
    unsigned short* VTb   = (unsigned short*)(ws + (40u << 20)); // 8 MB

    prep<<<16384, 256, 0, stream>>>(x, xz, mask, (unsigned int*)m8,
                                    Wqkv, wqkvT, Wout, woutT);
    gemm_bf16<0, 256><<<dim3(3072 / 128, 4096 / 256), 512, 0, stream>>>(
        xz, wqkvT, 4096, 3072, 1024, Qb, Kb, VTb, nullptr, nullptr);
    flash_attn<<<dim3(16, 32), 512, 0, stream>>>(Qb, Kb, VTb, m8, xz);
    gemm_bf16<1, 128><<<dim3(1024 / 128, 4096 / 128), 256, 0, stream>>>(
        xz, woutT, 4096, 1024, 1024, nullptr, nullptr, nullptr, bout, out);
}